// Round 2
// baseline (505.703 us; speedup 1.0000x reference)
//
#include <hip/hip_runtime.h>
#include <cstdint>
#include <cstddef>

// Match XLA: no FMA contraction anywhere in this TU (mul and add rounded separately).
#pragma clang fp contract(off)

#define N_PIX    524288     // 8*256*256 output pixels
#define CSPLANES 112        // 4*28 reduced planes
#define PLANE    65536      // 256*256
#define DCH      48         // max PRNG-loop depth (P(exceed) ~ 1e-30)

// ---------------- Threefry-2x32 (exact JAX semantics) ----------------
struct TF2 { uint32_t a, b; };

__host__ __device__ constexpr uint32_t rotl32(uint32_t x, int d) {
  return (x << d) | (x >> (32 - d));
}

__host__ __device__ constexpr TF2 threefry(uint32_t k0, uint32_t k1,
                                           uint32_t c0, uint32_t c1) {
  uint32_t ks2 = k0 ^ k1 ^ 0x1BD11BDAu;
  uint32_t x0 = c0 + k0;
  uint32_t x1 = c1 + k1;
  const int R0[4] = {13, 15, 26, 6};
  const int R1[4] = {17, 29, 16, 24};
  for (int i = 0; i < 4; ++i) { x0 += x1; x1 = rotl32(x1, R0[i]); x1 ^= x0; }
  x0 += k1;  x1 += ks2 + 1u;
  for (int i = 0; i < 4; ++i) { x0 += x1; x1 = rotl32(x1, R1[i]); x1 ^= x0; }
  x0 += ks2; x1 += k0 + 2u;
  for (int i = 0; i < 4; ++i) { x0 += x1; x1 = rotl32(x1, R0[i]); x1 ^= x0; }
  x0 += k0;  x1 += k1 + 3u;
  for (int i = 0; i < 4; ++i) { x0 += x1; x1 = rotl32(x1, R1[i]); x1 ^= x0; }
  x0 += k1;  x1 += ks2 + 4u;
  for (int i = 0; i < 4; ++i) { x0 += x1; x1 = rotl32(x1, R0[i]); x1 ^= x0; }
  x0 += ks2; x1 += k0 + 5u;
  return TF2{x0, x1};
}

// Key chains for the samplers, computed at COMPILE TIME (key = jax.random.key(1)).
// Convention: jax_threefry_partitionable = True (default since jax 0.4.36):
//   split(key, n)[i] = threefry(key, (0, i));  random_bits[j] = x0^x1 of threefry(key, (0, j))
struct Chains {
  uint32_t kg0, kg1;                                   // normal key
  uint32_t rj0a[DCH], rj0b[DCH], rj1a[DCH], rj1b[DCH]; // rejection split-3 chain from kp
  uint32_t kda[DCH], kdb[DCH];                         // knuth split-2 chain from kd
  uint32_t kpa[DCH], kpb[DCH];                         // knuth split-2 chain from kp (lam<10 fallback)
};

__host__ __device__ constexpr Chains make_chains() {
  Chains c{};
  TF2 kp = threefry(0u, 1u, 0u, 0u);   // split(key(1), 3) rows 0..2
  TF2 kd = threefry(0u, 1u, 0u, 1u);
  TF2 kg = threefry(0u, 1u, 0u, 2u);
  c.kg0 = kg.a; c.kg1 = kg.b;
  {
    uint32_t a = kp.a, b = kp.b;
    for (int i = 0; i < DCH; ++i) {
      TF2 nk = threefry(a, b, 0u, 0u);
      TF2 s0 = threefry(a, b, 0u, 1u);
      TF2 s1 = threefry(a, b, 0u, 2u);
      c.rj0a[i] = s0.a; c.rj0b[i] = s0.b;
      c.rj1a[i] = s1.a; c.rj1b[i] = s1.b;
      a = nk.a; b = nk.b;
    }
  }
  {
    uint32_t a = kd.a, b = kd.b;
    for (int i = 0; i < DCH; ++i) {
      TF2 nk = threefry(a, b, 0u, 0u);
      TF2 sk = threefry(a, b, 0u, 1u);
      c.kda[i] = sk.a; c.kdb[i] = sk.b;
      a = nk.a; b = nk.b;
    }
  }
  {
    uint32_t a = kp.a, b = kp.b;
    for (int i = 0; i < DCH; ++i) {
      TF2 nk = threefry(a, b, 0u, 0u);
      TF2 sk = threefry(a, b, 0u, 1u);
      c.kpa[i] = sk.a; c.kpb[i] = sk.b;
      a = nk.a; b = nk.b;
    }
  }
  return c;
}

__constant__ Chains G = make_chains();

// uniform [0,1) for flat element j under a given key (partitionable bit path)
__device__ inline float u01(uint32_t k0, uint32_t k1, uint32_t j) {
  TF2 r = threefry(k0, k1, 0u, j);
  uint32_t bits = r.a ^ r.b;
  return __uint_as_float((bits >> 9) | 0x3F800000u) - 1.0f;
}

// ---------------- XLA-exact special functions (f32, Lanczos / Giles) ----------------
__device__ inline float xla_lgamma(float x_in) {
  // no-reflection path only (argument k+1 >= 1 whenever the result matters)
  float z = x_in - 1.0f;
  float x = 1.0f;  // f32(kBaseLanczosCoeff)
  x = x + 676.520368121885098567009190444019f    / ((z + 0.0f) + 1.0f);
  x = x + (-1259.13921672240287047156078755283f) / ((z + 1.0f) + 1.0f);
  x = x + 771.3234287776530788486528258894f      / ((z + 2.0f) + 1.0f);
  x = x + (-176.61502916214059906584551354f)     / ((z + 3.0f) + 1.0f);
  x = x + 12.507343278686904814458936853f        / ((z + 4.0f) + 1.0f);
  x = x + (-0.13857109526572011689554707f)       / ((z + 5.0f) + 1.0f);
  x = x + 9.984369578019570859563e-6f            / ((z + 6.0f) + 1.0f);
  x = x + 1.50563273514931155834e-7f             / ((z + 7.0f) + 1.0f);
  float t = 7.5f + z;
  float log_t = 2.0149030205422647f + log1pf(z / 7.5f);
  return 0.91893853320467274178f + ((z + 0.5f) - t / log_t) * log_t + logf(x);
}

__device__ inline float xla_erfinv(float xx) {  // Giles 2012, as in XLA ErfInv32
  float w = -log1pf(-(xx * xx));
  float p;
  if (w < 5.0f) {
    float ww = w - 2.5f;
    p = 2.81022636e-08f;
    p = 3.43273939e-07f + p * ww;
    p = -3.5233877e-06f + p * ww;
    p = -4.39150654e-06f + p * ww;
    p = 0.00021858087f + p * ww;
    p = -0.00125372503f + p * ww;
    p = -0.00417768164f + p * ww;
    p = 0.246640727f + p * ww;
    p = 1.50140941f + p * ww;
  } else {
    float ww = sqrtf(w) - 3.0f;
    p = -0.000200214257f;
    p = 0.000100950558f + p * ww;
    p = 0.00134934322f + p * ww;
    p = -0.00367342844f + p * ww;
    p = 0.00573950773f + p * ww;
    p = -0.0076224613f + p * ww;
    p = 0.00943887047f + p * ww;
    p = 1.00167406f + p * ww;
    p = 2.83297682f + p * ww;
  }
  return p * xx;
}

__device__ inline float xla_normal(uint32_t j) {   // jax.random.normal(kg)[j]
  const float lo = -0.999999940395355224609375f;   // nextafter(-1, 0) in f32
  float f = u01(G.kg0, G.kg1, j);
  float u = f * (1.0f - lo) + lo;                  // (1-lo) folds to 2.0f, XLA-identical
  u = fmaxf(lo, u);
  return 1.41421356237309504880f * xla_erfinv(u);  // f32(np.sqrt(2))
}

// ---------------- JAX poisson samplers ----------------
__device__ inline int knuth_sample(const uint32_t* ka, const uint32_t* kb,
                                   uint32_t j, float lam) {
  const float neg = -lam;
  int k = 0;
  float lp = 0.0f;
  #pragma unroll 1
  for (int i = 0; i < DCH; ++i) {
    if (!(lp > neg)) break;
    ++k;
    float uu = u01(ka[i], kb[i], j);
    lp = lp + logf(uu);
  }
  return k - 1;
}

struct RejC { float lam, loglam, a, b, inva, vr; };

__device__ inline RejC make_rc(float lam) {
  RejC rc;
  rc.lam = lam;
  rc.loglam = logf(lam);
  rc.b = 0.931f + 2.53f * sqrtf(lam);
  rc.a = -0.059f + 0.02483f * rc.b;
  rc.inva = 1.1239f + 1.1328f / (rc.b - 3.4f);
  rc.vr = 0.9277f - 3.6224f / (rc.b - 2.0f);
  return rc;
}

// One body of jax's _poisson_rejection while-loop (iteration index i, 0-based)
__device__ inline bool rej_step(const RejC& rc, uint32_t j, int i, float* kout) {
  float u = u01(G.rj0a[i], G.rj0b[i], j) - 0.5f;
  float v = u01(G.rj1a[i], G.rj1b[i], j);
  float us = 0.5f - fabsf(u);
  float k = floorf(((2.0f * rc.a / us + rc.b) * u + rc.lam) + 0.43f);
  *kout = k;
  bool accept1 = (us >= 0.07f) && (v <= rc.vr);
  if (accept1) return true;
  bool reject = (k < 0.0f) || ((us < 0.013f) && (v > us));
  if (reject) return false;
  float s = logf(v * rc.inva / (rc.a / (us * us) + rc.b));
  float t = (-rc.lam + k * rc.loglam) - xla_lgamma(k + 1.0f);
  return s <= t;
}

// ---------------- Kernel 1: pure streaming reduction -> cap ----------------
// Block = 256 threads = 4 waves. Wave w handles planes [28w, 28w+28) for the
// block's 256 pixels (lane l -> pixel group of 4, float4 loads, 1KB/wave/inst).
// LDS combine, per-thread final sum, write cap to out[N_PIX + j].
__global__ __launch_bounds__(256, 8) void reduce_kernel(const float* __restrict__ spec,
                                                        const float* __restrict__ filt,
                                                        float* __restrict__ out) {
  const int tid = threadIdx.x;
  const int w = tid >> 6;          // wave 0..3 -> plane quarter
  const int l = tid & 63;          // lane -> pixel group
  const int pixbase = blockIdx.x << 8;           // 256 pixels per block
  const int b_img = pixbase >> 16;               // blocks never straddle a batch
  const int hw = (pixbase & 65535) + (l << 2);
  const size_t base = (size_t)b_img * ((size_t)CSPLANES * PLANE)
                    + (size_t)(w * 28) * PLANE + (size_t)hw;
  const float* sp = spec + base;
  const float* fp = filt + base;

  float ax = 0.f, ay = 0.f, az = 0.f, aw = 0.f;
  #pragma unroll 4
  for (int cs = 0; cs < 28; ++cs) {
    const float4 s = *reinterpret_cast<const float4*>(sp + (size_t)cs * PLANE);
    const float4 f = *reinterpret_cast<const float4*>(fp + (size_t)cs * PLANE);
    ax += s.x * f.x; ay += s.y * f.y; az += s.z * f.z; aw += s.w * f.w;
  }

  __shared__ float part[4][64][4];     // [wave][group][component] = 4KB
  part[w][l][0] = ax; part[w][l][1] = ay; part[w][l][2] = az; part[w][l][3] = aw;
  __syncthreads();

  // thread t finishes pixel pixbase + t; word index = w*256 + t -> conflict-free
  const int g = tid >> 2, c = tid & 3;
  float c0 = part[0][g][c];
  float c1 = part[1][g][c];
  float c2 = part[2][g][c];
  float c3 = part[3][g][c];
  float cap = ((c0 + c1) + c2) + c3;
  out[N_PIX + pixbase + tid] = cap;
}

// ---------------- Kernel 2: noise synthesis + global T ----------------
__global__ __launch_bounds__(256) void noise_kernel(float* __restrict__ out,
                                                    unsigned* __restrict__ tslot) {
  const uint32_t j = blockIdx.x * 256u + threadIdx.x;
  const float cap = out[N_PIX + j];
  const float peak = cap + 1e-10f;
  out[N_PIX + j] = peak;                               // output 1: peak
  out[j] = (float)knuth_sample(G.kda, G.kdb, j, 0.5f); // temp: dnoisy
  out[2 * N_PIX + j] = xla_normal(j) * 0.5f;           // temp: gnoisy

  RejC rc = make_rc(peak);
  unsigned F = DCH;
  #pragma unroll 1
  for (int i = 0; i < DCH; ++i) {   // first-accept iteration (jax's global T input)
    float kc;
    if (rej_step(rc, j, i, &kc)) { F = (unsigned)(i + 1); break; }
  }

  for (int off = 32; off; off >>= 1) {
    unsigned o = (unsigned)__shfl_down((int)F, off, 64);
    F = F > o ? F : o;
  }
  __shared__ unsigned sred[4];
  if ((threadIdx.x & 63) == 0) sred[threadIdx.x >> 6] = F;
  __syncthreads();
  if (threadIdx.x == 0) {
    unsigned m0 = sred[0] > sred[1] ? sred[0] : sred[1];
    unsigned m1 = sred[2] > sred[3] ? sred[2] : sred[3];
    unsigned m = m0 > m1 ? m0 : m1;
    atomicMax(tslot, m);
  }
}

// ---------------- Kernel 3: resolve pnoisy (last accept <= T) + final outputs ----------------
__global__ __launch_bounds__(256) void resolve_kernel(float* __restrict__ out,
                                                      const unsigned* __restrict__ tslot) {
  const uint32_t j = blockIdx.x * 256u + threadIdx.x;
  const int T = (int)(*tslot);
  const float peak = out[N_PIX + j];
  const float d = out[j];
  const float g = out[2 * N_PIX + j];
  float pv;
  if (peak >= 10.0f) {
    RejC rc = make_rc(peak);
    float kk = -1.0f;
    #pragma unroll 1
    for (int i = T - 1; i >= 0; --i) {   // downward scan: first hit = last accept <= T
      float kc;
      if (rej_step(rc, j, i, &kc)) { kk = kc; break; }
    }
    pv = (float)(int)kk;
  } else if (peak <= 0.0f) {
    pv = 0.0f;
  } else {
    pv = (float)knuth_sample(G.kpa, G.kpb, j, peak);
  }
  const float noisy = ((pv + d) + g) * 10.0f / 255.0f;
  out[j] = noisy;               // output 0
  out[2 * N_PIX + j] = 0.5f;    // output 2: dark_t
  out[3 * N_PIX + j] = 0.25f;   // output 3: gauss_t^2
}

extern "C" void kernel_launch(void* const* d_in, const int* in_sizes, int n_in,
                              void* d_out, int out_size, void* d_ws, size_t ws_size,
                              hipStream_t stream) {
  (void)in_sizes; (void)n_in; (void)out_size; (void)ws_size;
  const float* spec = (const float*)d_in[0];
  const float* filt = (const float*)d_in[1];
  float* out = (float*)d_out;
  unsigned* tslot = (unsigned*)d_ws;
  (void)hipMemsetAsync(d_ws, 0, sizeof(unsigned), stream);
  hipLaunchKernelGGL(reduce_kernel, dim3(N_PIX / 256), dim3(256), 0, stream,
                     spec, filt, out);
  hipLaunchKernelGGL(noise_kernel, dim3(N_PIX / 256), dim3(256), 0, stream,
                     out, tslot);
  hipLaunchKernelGGL(resolve_kernel, dim3(N_PIX / 256), dim3(256), 0, stream,
                     out, tslot);
}

// Round 3
// 500.805 us; speedup vs baseline: 1.0098x; 1.0098x over previous
//
#include <hip/hip_runtime.h>
#include <cstdint>
#include <cstddef>

// Match XLA: no FMA contraction anywhere in this TU (mul and add rounded separately).
#pragma clang fp contract(off)

#define N_PIX    524288     // 8*256*256 output pixels
#define CSPLANES 112        // 4*28 reduced planes
#define PLANE    65536      // 256*256
#define DCH      48         // max PRNG-loop depth (P(exceed) ~ 1e-30)
#define NBLK     256        // fused-kernel grid: all co-resident (262144 thr = 50% chip)

// ---------------- Threefry-2x32 (exact JAX semantics) ----------------
struct TF2 { uint32_t a, b; };

__host__ __device__ constexpr uint32_t rotl32(uint32_t x, int d) {
  return (x << d) | (x >> (32 - d));
}

__host__ __device__ constexpr TF2 threefry(uint32_t k0, uint32_t k1,
                                           uint32_t c0, uint32_t c1) {
  uint32_t ks2 = k0 ^ k1 ^ 0x1BD11BDAu;
  uint32_t x0 = c0 + k0;
  uint32_t x1 = c1 + k1;
  const int R0[4] = {13, 15, 26, 6};
  const int R1[4] = {17, 29, 16, 24};
  for (int i = 0; i < 4; ++i) { x0 += x1; x1 = rotl32(x1, R0[i]); x1 ^= x0; }
  x0 += k1;  x1 += ks2 + 1u;
  for (int i = 0; i < 4; ++i) { x0 += x1; x1 = rotl32(x1, R1[i]); x1 ^= x0; }
  x0 += ks2; x1 += k0 + 2u;
  for (int i = 0; i < 4; ++i) { x0 += x1; x1 = rotl32(x1, R0[i]); x1 ^= x0; }
  x0 += k0;  x1 += k1 + 3u;
  for (int i = 0; i < 4; ++i) { x0 += x1; x1 = rotl32(x1, R1[i]); x1 ^= x0; }
  x0 += k1;  x1 += ks2 + 4u;
  for (int i = 0; i < 4; ++i) { x0 += x1; x1 = rotl32(x1, R0[i]); x1 ^= x0; }
  x0 += ks2; x1 += k0 + 5u;
  return TF2{x0, x1};
}

// Key chains for the samplers, computed at COMPILE TIME (key = jax.random.key(1)).
// Convention: jax_threefry_partitionable = True (default since jax 0.4.36):
//   split(key, n)[i] = threefry(key, (0, i));  random_bits[j] = x0^x1 of threefry(key, (0, j))
struct Chains {
  uint32_t kg0, kg1;                                   // normal key
  uint32_t rj0a[DCH], rj0b[DCH], rj1a[DCH], rj1b[DCH]; // rejection split-3 chain from kp
  uint32_t kda[DCH], kdb[DCH];                         // knuth split-2 chain from kd
  uint32_t kpa[DCH], kpb[DCH];                         // knuth split-2 chain from kp (lam<10 fallback)
};

__host__ __device__ constexpr Chains make_chains() {
  Chains c{};
  TF2 kp = threefry(0u, 1u, 0u, 0u);   // split(key(1), 3) rows 0..2
  TF2 kd = threefry(0u, 1u, 0u, 1u);
  TF2 kg = threefry(0u, 1u, 0u, 2u);
  c.kg0 = kg.a; c.kg1 = kg.b;
  {
    uint32_t a = kp.a, b = kp.b;
    for (int i = 0; i < DCH; ++i) {
      TF2 nk = threefry(a, b, 0u, 0u);
      TF2 s0 = threefry(a, b, 0u, 1u);
      TF2 s1 = threefry(a, b, 0u, 2u);
      c.rj0a[i] = s0.a; c.rj0b[i] = s0.b;
      c.rj1a[i] = s1.a; c.rj1b[i] = s1.b;
      a = nk.a; b = nk.b;
    }
  }
  {
    uint32_t a = kd.a, b = kd.b;
    for (int i = 0; i < DCH; ++i) {
      TF2 nk = threefry(a, b, 0u, 0u);
      TF2 sk = threefry(a, b, 0u, 1u);
      c.kda[i] = sk.a; c.kdb[i] = sk.b;
      a = nk.a; b = nk.b;
    }
  }
  {
    uint32_t a = kp.a, b = kp.b;
    for (int i = 0; i < DCH; ++i) {
      TF2 nk = threefry(a, b, 0u, 0u);
      TF2 sk = threefry(a, b, 0u, 1u);
      c.kpa[i] = sk.a; c.kpb[i] = sk.b;
      a = nk.a; b = nk.b;
    }
  }
  return c;
}

__constant__ Chains G = make_chains();

// uniform [0,1) for flat element j under a given key (partitionable bit path)
__device__ inline float u01(uint32_t k0, uint32_t k1, uint32_t j) {
  TF2 r = threefry(k0, k1, 0u, j);
  uint32_t bits = r.a ^ r.b;
  return __uint_as_float((bits >> 9) | 0x3F800000u) - 1.0f;
}

// ---------------- XLA-exact special functions (f32, Lanczos / Giles) ----------------
__device__ inline float xla_lgamma(float x_in) {
  // no-reflection path only (argument k+1 >= 1 whenever the result matters)
  float z = x_in - 1.0f;
  float x = 1.0f;  // f32(kBaseLanczosCoeff)
  x = x + 676.520368121885098567009190444019f    / ((z + 0.0f) + 1.0f);
  x = x + (-1259.13921672240287047156078755283f) / ((z + 1.0f) + 1.0f);
  x = x + 771.3234287776530788486528258894f      / ((z + 2.0f) + 1.0f);
  x = x + (-176.61502916214059906584551354f)     / ((z + 3.0f) + 1.0f);
  x = x + 12.507343278686904814458936853f        / ((z + 4.0f) + 1.0f);
  x = x + (-0.13857109526572011689554707f)       / ((z + 5.0f) + 1.0f);
  x = x + 9.984369578019570859563e-6f            / ((z + 6.0f) + 1.0f);
  x = x + 1.50563273514931155834e-7f             / ((z + 7.0f) + 1.0f);
  float t = 7.5f + z;
  float log_t = 2.0149030205422647f + log1pf(z / 7.5f);
  return 0.91893853320467274178f + ((z + 0.5f) - t / log_t) * log_t + logf(x);
}

__device__ inline float xla_erfinv(float xx) {  // Giles 2012, as in XLA ErfInv32
  float w = -log1pf(-(xx * xx));
  float p;
  if (w < 5.0f) {
    float ww = w - 2.5f;
    p = 2.81022636e-08f;
    p = 3.43273939e-07f + p * ww;
    p = -3.5233877e-06f + p * ww;
    p = -4.39150654e-06f + p * ww;
    p = 0.00021858087f + p * ww;
    p = -0.00125372503f + p * ww;
    p = -0.00417768164f + p * ww;
    p = 0.246640727f + p * ww;
    p = 1.50140941f + p * ww;
  } else {
    float ww = sqrtf(w) - 3.0f;
    p = -0.000200214257f;
    p = 0.000100950558f + p * ww;
    p = 0.00134934322f + p * ww;
    p = -0.00367342844f + p * ww;
    p = 0.00573950773f + p * ww;
    p = -0.0076224613f + p * ww;
    p = 0.00943887047f + p * ww;
    p = 1.00167406f + p * ww;
    p = 2.83297682f + p * ww;
  }
  return p * xx;
}

__device__ inline float xla_normal(uint32_t j) {   // jax.random.normal(kg)[j]
  const float lo = -0.999999940395355224609375f;   // nextafter(-1, 0) in f32
  float f = u01(G.kg0, G.kg1, j);
  float u = f * (1.0f - lo) + lo;                  // (1-lo) folds to 2.0f, XLA-identical
  u = fmaxf(lo, u);
  return 1.41421356237309504880f * xla_erfinv(u);  // f32(np.sqrt(2))
}

// ---------------- JAX poisson samplers ----------------
__device__ inline int knuth_sample(const uint32_t* ka, const uint32_t* kb,
                                   uint32_t j, float lam) {
  const float neg = -lam;
  int k = 0;
  float lp = 0.0f;
  #pragma unroll 1
  for (int i = 0; i < DCH; ++i) {
    if (!(lp > neg)) break;
    ++k;
    float uu = u01(ka[i], kb[i], j);
    lp = lp + logf(uu);
  }
  return k - 1;
}

struct RejC { float lam, loglam, a, b, inva, vr; };

__device__ inline RejC make_rc(float lam) {
  RejC rc;
  rc.lam = lam;
  rc.loglam = logf(lam);
  rc.b = 0.931f + 2.53f * sqrtf(lam);
  rc.a = -0.059f + 0.02483f * rc.b;
  rc.inva = 1.1239f + 1.1328f / (rc.b - 3.4f);
  rc.vr = 0.9277f - 3.6224f / (rc.b - 2.0f);
  return rc;
}

// One body of jax's _poisson_rejection while-loop (iteration index i, 0-based)
__device__ inline bool rej_step(const RejC& rc, uint32_t j, int i, float* kout) {
  float u = u01(G.rj0a[i], G.rj0b[i], j) - 0.5f;
  float v = u01(G.rj1a[i], G.rj1b[i], j);
  float us = 0.5f - fabsf(u);
  float k = floorf(((2.0f * rc.a / us + rc.b) * u + rc.lam) + 0.43f);
  *kout = k;
  bool accept1 = (us >= 0.07f) && (v <= rc.vr);
  if (accept1) return true;
  bool reject = (k < 0.0f) || ((us < 0.013f) && (v > us));
  if (reject) return false;
  float s = logf(v * rc.inva / (rc.a / (us * us) + rc.b));
  float t = (-rc.lam + k * rc.loglam) - xla_lgamma(k + 1.0f);
  return s <= t;
}

__device__ inline unsigned first_accept(const RejC& rc, uint32_t j) {
  unsigned F = DCH;
  #pragma unroll 1
  for (int i = 0; i < DCH; ++i) {   // first-accept iteration (jax's global T input)
    float kc;
    if (rej_step(rc, j, i, &kc)) { F = (unsigned)(i + 1); break; }
  }
  return F;
}

__device__ inline float resolve_pix(const RejC& rc, float peak, uint32_t j, int T) {
  if (peak >= 10.0f) {
    float kk = -1.0f;
    #pragma unroll 1
    for (int i = T - 1; i >= 0; --i) {   // downward scan: first hit = last accept <= T
      float kc;
      if (rej_step(rc, j, i, &kc)) { kk = kc; break; }
    }
    return (float)(int)kk;
  } else if (peak <= 0.0f) {
    return 0.0f;
  } else {
    return (float)knuth_sample(G.kpa, G.kpb, j, peak);
  }
}

// ---------------- Fused kernel: reduce -> noise -> grid barrier (T) -> resolve ----------------
// Grid = 256 blocks x 1024 threads. Block owns 2048 contiguous pixels -> 8KB
// contiguous chunk per array per plane iteration (vs 1KB round 2). All blocks
// co-resident by capacity (262144 of 524288 threads) -> spin barrier is safe.
// sync[0] = global T (atomicMax), sync[1] = arrival count.
__global__ __launch_bounds__(1024) void fused_kernel(const float* __restrict__ spec,
                                                     const float* __restrict__ filt,
                                                     float* __restrict__ out,
                                                     unsigned* __restrict__ sync) {
  const int tid = threadIdx.x;
  const int pixbase = blockIdx.x << 11;          // 2048 pixels per block
  const int b_img = pixbase >> 16;               // blocks never straddle a batch
  const int hw = (pixbase & 65535) + (tid << 1);
  const size_t base = (size_t)b_img * ((size_t)CSPLANES * PLANE) + (size_t)hw;
  const float* sp = spec + base;
  const float* fp = filt + base;

  float a0 = 0.f, a1 = 0.f;
  #pragma unroll 8
  for (int cs = 0; cs < CSPLANES; ++cs) {        // serial-112 order == round-1 (absmax 0.43)
    const float2 s = *reinterpret_cast<const float2*>(sp + (size_t)cs * PLANE);
    const float2 f = *reinterpret_cast<const float2*>(fp + (size_t)cs * PLANE);
    a0 += s.x * f.x;
    a1 += s.y * f.y;
  }

  const uint32_t j0 = (uint32_t)(pixbase + (tid << 1));
  const uint32_t j1 = j0 + 1u;
  const float pk0 = a0 + 1e-10f;
  const float pk1 = a1 + 1e-10f;
  const float d0 = (float)knuth_sample(G.kda, G.kdb, j0, 0.5f);
  const float d1 = (float)knuth_sample(G.kda, G.kdb, j1, 0.5f);
  const float g0 = xla_normal(j0) * 0.5f;
  const float g1 = xla_normal(j1) * 0.5f;
  const RejC rc0 = make_rc(pk0);
  const RejC rc1 = make_rc(pk1);
  unsigned F0 = first_accept(rc0, j0);
  unsigned F1 = first_accept(rc1, j1);
  unsigned F = F0 > F1 ? F0 : F1;

  // wave max -> block max -> device max + arrival barrier
  for (int off = 32; off; off >>= 1) {
    unsigned o = (unsigned)__shfl_down((int)F, off, 64);
    F = F > o ? F : o;
  }
  __shared__ unsigned sred[16];
  __shared__ int sT;
  if ((tid & 63) == 0) sred[tid >> 6] = F;
  __syncthreads();
  if (tid == 0) {
    unsigned m = sred[0];
    #pragma unroll
    for (int i = 1; i < 16; ++i) m = m > sred[i] ? m : sred[i];
    __hip_atomic_fetch_max(&sync[0], m, __ATOMIC_RELAXED, __HIP_MEMORY_SCOPE_AGENT);
    __hip_atomic_fetch_add(&sync[1], 1u, __ATOMIC_ACQ_REL, __HIP_MEMORY_SCOPE_AGENT);
    while (__hip_atomic_load(&sync[1], __ATOMIC_ACQUIRE, __HIP_MEMORY_SCOPE_AGENT) < (unsigned)NBLK) {
      __builtin_amdgcn_s_sleep(8);
    }
    sT = (int)__hip_atomic_load(&sync[0], __ATOMIC_RELAXED, __HIP_MEMORY_SCOPE_AGENT);
  }
  __syncthreads();
  const int T = sT;

  const float pv0 = resolve_pix(rc0, pk0, j0, T);
  const float pv1 = resolve_pix(rc1, pk1, j1, T);
  const float n0 = ((pv0 + d0) + g0) * 10.0f / 255.0f;
  const float n1 = ((pv1 + d1) + g1) * 10.0f / 255.0f;

  *reinterpret_cast<float2*>(out + j0)             = make_float2(n0, n1);      // output 0: noisy
  *reinterpret_cast<float2*>(out + N_PIX + j0)     = make_float2(pk0, pk1);    // output 1: peak
  *reinterpret_cast<float2*>(out + 2 * N_PIX + j0) = make_float2(0.5f, 0.5f);  // output 2: dark_t
  *reinterpret_cast<float2*>(out + 3 * N_PIX + j0) = make_float2(0.25f, 0.25f);// output 3: gauss_t^2
}

extern "C" void kernel_launch(void* const* d_in, const int* in_sizes, int n_in,
                              void* d_out, int out_size, void* d_ws, size_t ws_size,
                              hipStream_t stream) {
  (void)in_sizes; (void)n_in; (void)out_size; (void)ws_size;
  const float* spec = (const float*)d_in[0];
  const float* filt = (const float*)d_in[1];
  float* out = (float*)d_out;
  unsigned* sync = (unsigned*)d_ws;
  (void)hipMemsetAsync(d_ws, 0, 2 * sizeof(unsigned), stream);
  hipLaunchKernelGGL(fused_kernel, dim3(NBLK), dim3(1024), 0, stream,
                     spec, filt, out, sync);
}